// Round 1
// baseline (140.022 us; speedup 1.0000x reference)
//
#include <hip/hip_runtime.h>
#include <hip/hip_bf16.h>

constexpr int B = 2, S = 2048, D = 1024;
constexpr int H = 16, KVH = 4, HD = 64;
constexpr int BS = B * S;                 // 4096
constexpr int QS = 1536;                  // fused qkv width

typedef __attribute__((ext_vector_type(8))) short short8;
typedef __attribute__((ext_vector_type(4))) float floatx4;

#define GPTR(p) ((__attribute__((address_space(1))) void*)(p))
#define LPTR(p) ((__attribute__((address_space(3))) void*)(p))

static __device__ __forceinline__ unsigned short f2bf(float f) {
  union { float f; unsigned u; } c{f};
  unsigned r = (c.u + 0x7FFFu + ((c.u >> 16) & 1u)) >> 16;
  return (unsigned short)r;
}

// ---------------------------------------------------------------------------
// Prep: x fp32 -> bf16 (blocks [0,4096)) and all 4 weight transposes
// (blocks [4096, 4096+2560)). fp32 [K=1024,N] -> bf16 [N,1024].
// ---------------------------------------------------------------------------
__global__ __launch_bounds__(256) void prep_kernel(
    const float* __restrict__ x,
    const float* __restrict__ wq, const float* __restrict__ wk,
    const float* __restrict__ wv, const float* __restrict__ wo,
    unsigned short* __restrict__ xb,
    unsigned short* __restrict__ wqkvT, unsigned short* __restrict__ woT) {
  int bz = blockIdx.x;
  if (bz < 4096) {
    int t = bz * 256 + threadIdx.x;
    float4 v = ((const float4*)x)[t];
    ushort4 o;
    o.x = f2bf(v.x); o.y = f2bf(v.y); o.z = f2bf(v.z); o.w = f2bf(v.w);
    ((ushort4*)xb)[t] = o;
    return;
  }
  __shared__ float t[32][33];
  int z = bz - 4096;                 // 0..2559
  int zx = z % 80, zy = z / 80;      // region-select, k-block
  const float* src; unsigned short* dst; int N, dstOff, nb;
  if (zx < 32)      { src = wq; dst = wqkvT; N = 1024; dstOff = 0;    nb = zx; }
  else if (zx < 40) { src = wk; dst = wqkvT; N = 256;  dstOff = 1024; nb = zx - 32; }
  else if (zx < 48) { src = wv; dst = wqkvT; N = 256;  dstOff = 1280; nb = zx - 40; }
  else              { src = wo; dst = woT;   N = 1024; dstOff = 0;    nb = zx - 48; }
  int n0 = nb * 32, k0 = zy * 32;
  int tx = threadIdx.x & 31, ty = threadIdx.x >> 5;
#pragma unroll
  for (int r = 0; r < 4; ++r)
    t[ty + r * 8][tx] = src[(size_t)(k0 + ty + r * 8) * N + n0 + tx];
  __syncthreads();
#pragma unroll
  for (int r = 0; r < 4; ++r)
    dst[(size_t)(dstOff + n0 + ty + r * 8) * D + k0 + tx] = f2bf(t[tx][ty + r * 8]);
}

// ---------------------------------------------------------------------------
// Shared GEMM K-loop: m97-exact structure. 128x128 tile, BK=64 (two 32-k
// sections, linear [row][32] LDS layout), async global_load_lds width-16
// staging, 4 waves at 64x64 each (acc[4][4], MFMA:ds_read density 16:8).
// Grid: blockIdx.x = ROW tile, .y = COL tile.
// ---------------------------------------------------------------------------
#define GEMM_PROLOGUE(Aptr, Btptr)                                            \
  __shared__ unsigned short As[2 * 128 * 32];                                 \
  __shared__ unsigned short Bs[2 * 128 * 32];                                 \
  const int tid = threadIdx.x;                                                \
  const int lane = tid & 63, wvid = tid >> 6;                                 \
  const int wy = wvid >> 1, wx = wvid & 1;                                    \
  const int quad = lane >> 4, lrow = lane & 15;                               \
  const size_t row0 = (size_t)blockIdx.x * 128;                               \
  const size_t col0 = (size_t)blockIdx.y * 128;                               \
  floatx4 acc[4][4];                                                          \
  _Pragma("unroll") for (int i = 0; i < 4; ++i)                               \
    _Pragma("unroll") for (int j = 0; j < 4; ++j)                             \
      acc[i][j] = floatx4{0.f, 0.f, 0.f, 0.f};                                \
  const int srow = wvid * 32 + (lane >> 2);                                   \
  const int schk = (lane & 3) * 8;                                            \
  const unsigned short* gA = (Aptr) + (row0 + srow) * 1024 + schk;            \
  const unsigned short* gB = (Btptr) + (col0 + srow) * 1024 + schk;           \
  char* ldsA = (char*)As + wvid * 2048;                                       \
  char* ldsB = (char*)Bs + wvid * 2048;                                       \
  for (int k0 = 0; k0 < 1024; k0 += 64) {                                     \
    __syncthreads();                                                          \
    _Pragma("unroll") for (int hf = 0; hf < 2; ++hf) {                        \
      __builtin_amdgcn_global_load_lds(GPTR(gA + k0 + hf * 32),               \
                                       LPTR(ldsA + hf * 8192), 16, 0, 0);     \
      __builtin_amdgcn_global_load_lds(GPTR(gA + 16 * 1024 + k0 + hf * 32),   \
                                       LPTR(ldsA + hf * 8192 + 1024), 16, 0, 0); \
      __builtin_amdgcn_global_load_lds(GPTR(gB + k0 + hf * 32),               \
                                       LPTR(ldsB + hf * 8192), 16, 0, 0);     \
      __builtin_amdgcn_global_load_lds(GPTR(gB + 16 * 1024 + k0 + hf * 32),   \
                                       LPTR(ldsB + hf * 8192 + 1024), 16, 0, 0); \
    }                                                                         \
    __syncthreads();                                                          \
    _Pragma("unroll") for (int hf = 0; hf < 2; ++hf) {                        \
      short8 af[4], bg[4];                                                    \
      _Pragma("unroll") for (int mi = 0; mi < 4; ++mi)                        \
        af[mi] = *(const short8*)&As[hf * 4096 +                              \
                                     (wy * 64 + mi * 16 + lrow) * 32 + quad * 8]; \
      _Pragma("unroll") for (int ni = 0; ni < 4; ++ni)                        \
        bg[ni] = *(const short8*)&Bs[hf * 4096 +                              \
                                     (wx * 64 + ni * 16 + lrow) * 32 + quad * 8]; \
      _Pragma("unroll") for (int mi = 0; mi < 4; ++mi)                        \
        _Pragma("unroll") for (int ni = 0; ni < 4; ++ni)                      \
          acc[mi][ni] = __builtin_amdgcn_mfma_f32_16x16x32_bf16(              \
              af[mi], bg[ni], acc[mi][ni], 0, 0, 0);                          \
    }                                                                         \
  }

// ---------------------------------------------------------------------------
// Fused QKV GEMM + RoPE + V-transpose.  C[4096,1536] never materialized.
// Each wave owns exactly one 64-col head (col_wave % 64 == 0).
// ---------------------------------------------------------------------------
__global__ __launch_bounds__(256) void gemm_qkv_kernel(
    const unsigned short* __restrict__ A, const unsigned short* __restrict__ Bt,
    const float* __restrict__ cs, const float* __restrict__ sn,
    unsigned short* __restrict__ qb, unsigned short* __restrict__ kb,
    unsigned short* __restrict__ vt) {
  GEMM_PROLOGUE(A, Bt)

  const int col_wave = (int)col0 + wx * 64;     // wave-uniform, one full head
  const int h = col_wave >> 6;
  const int sb = (int)(row0 & 2047) + wy * 64;
  const int bidx = (int)(row0 >> 11);

  if (h < 20) {
    unsigned short* dst = (h < 16) ? qb : kb;
    const int dstride = (h < 16) ? 1024 : 256;
    const int dcol = (h < 16) ? col_wave : (col_wave - 1024);
    const bool ev = (lrow & 1) == 0;
#pragma unroll
    for (int mi = 0; mi < 4; ++mi) {
#pragma unroll
      for (int ni = 0; ni < 4; ++ni) {
        int ff = (ni * 16 + lrow) >> 1;
#pragma unroll
        for (int r = 0; r < 4; ++r) {
          int s = sb + mi * 16 + quad * 4 + r;
          float v = acc[mi][ni][r];
          float p = __shfl_xor(v, 1);
          float c = cs[s * 32 + ff];
          float si = sn[s * 32 + ff];
          float o = ev ? (v * c - p * si) : (v * c + p * si);
          size_t row = row0 + wy * 64 + mi * 16 + quad * 4 + r;
          dst[row * dstride + dcol + ni * 16 + lrow] = f2bf(o);
        }
      }
    }
  } else {
    const int kvh = h - 20;
    const int g = bidx * KVH + kvh;
#pragma unroll
    for (int mi = 0; mi < 4; ++mi) {
#pragma unroll
      for (int ni = 0; ni < 4; ++ni) {
        int d = ni * 16 + lrow;
        int s0 = sb + mi * 16 + quad * 4;
        ushort4 o;
        o.x = f2bf(acc[mi][ni][0]); o.y = f2bf(acc[mi][ni][1]);
        o.z = f2bf(acc[mi][ni][2]); o.w = f2bf(acc[mi][ni][3]);
        *(ushort4*)&vt[((size_t)(g * 64 + d)) * S + s0] = o;
      }
    }
  }
}

// ---------------------------------------------------------------------------
// Output projection GEMM -> fp32 C. Same structure.
// ---------------------------------------------------------------------------
__global__ __launch_bounds__(256) void gemm_bt_kernel(
    const unsigned short* __restrict__ A, const unsigned short* __restrict__ Bt,
    float* __restrict__ C, int N) {
  GEMM_PROLOGUE(A, Bt)

#pragma unroll
  for (int mi = 0; mi < 4; ++mi)
#pragma unroll
    for (int ni = 0; ni < 4; ++ni) {
      size_t col = col0 + wx * 64 + ni * 16 + lrow;
      size_t rowb = row0 + wy * 64 + mi * 16 + quad * 4;
#pragma unroll
      for (int r = 0; r < 4; ++r)
        C[(rowb + r) * N + col] = acc[mi][ni][r];
    }
}

// ---------------------------------------------------------------------------
// MFMA flash attention, block-cooperative K/V LDS staging.
// Block = 4 waves sharing (b, qblk, kvh); wave w handles head 4*kvh + w.
// K tile [96][72] (rows j = jbase..jbase+95, 2-way banking, b128-aligned),
// V^T tile [64][104]. j<0 rows/chunks clamped to 0 (masked or P=0).
// LDS total 40.4 KB -> 4 blocks/CU at grid 1024.
// ---------------------------------------------------------------------------
__global__ __launch_bounds__(256) void attn_kernel(
    const unsigned short* __restrict__ qb,   // [BS][1024]
    const unsigned short* __restrict__ kb,   // [BS][256]
    const unsigned short* __restrict__ vt,   // [B*KVH][64][S]
    unsigned short* __restrict__ ao) {       // [BS][1024]
  __shared__ __align__(16) unsigned short Ks[96 * 72];     // 13824 B
  __shared__ __align__(16) unsigned short Vs[64 * 104];    // 13312 B
  __shared__ __align__(16) unsigned short plds[4][16][104];// 13312 B
  const int tid = threadIdx.x;
  const int w = tid >> 6, lane = tid & 63;
  const int lrow = lane & 15, quad = lane >> 4;
  const int kvh = blockIdx.x & 3;           // shared across the 4 waves
  const int qblk = blockIdx.x >> 2;
  const int h = kvh * 4 + w;
  const int i0 = (qblk & (S / 16 - 1)) * 16;
  const int b = qblk >> 7;
  const int jbase = i0 - 80;
  const int bS = b * S;

  // ---- cooperative staging: K (96 chunks x 8) and V^T (64 x 12 chunks) ----
#pragma unroll
  for (int it = 0; it < 3; ++it) {
    int c = tid + it * 256;                 // 0..767
    int rr = c >> 3, oo = (c & 7) * 8;      // K: row rr (j = jbase+rr), cols oo..+7
    int j = jbase + rr;
    j = j < 0 ? 0 : j;                      // garbage masked later
    *(uint4*)&Ks[rr * 72 + oo] =
        *(const uint4*)&kb[(size_t)(bS + j) * 256 + kvh * 64 + oo];
  }
  const unsigned short* vbase = vt + (size_t)(b * KVH + kvh) * 64 * S;
#pragma unroll
  for (int it = 0; it < 3; ++it) {
    int c = tid + it * 256;                 // 0..767
    int rr = c / 12, oo = c % 12;           // V: d-row rr, j-chunk oo (8-aligned)
    int j = jbase + oo * 8;
    j = j < 0 ? 0 : j;                      // whole chunk <0 or >=0 (jbase%16==0)
    *(uint4*)&Vs[rr * 104 + oo * 8] = *(const uint4*)&vbase[(size_t)rr * S + j];
  }
  __syncthreads();

  // ---- QK^T (K frags from LDS) ----
  const unsigned short* qrow = qb + (size_t)(bS + i0 + lrow) * 1024 + h * 64 + quad * 8;
  short8 qf0 = *(const short8*)qrow;
  short8 qf1 = *(const short8*)(qrow + 32);

  floatx4 sc[6];
#pragma unroll
  for (int t = 0; t < 6; ++t) {
    int kr = t * 16 + lrow;
    short8 kf0 = *(const short8*)&Ks[kr * 72 + quad * 8];
    short8 kf1 = *(const short8*)&Ks[kr * 72 + 32 + quad * 8];
    floatx4 a = {0.f, 0.f, 0.f, 0.f};
    a = __builtin_amdgcn_mfma_f32_16x16x32_bf16(qf0, kf0, a, 0, 0, 0);
    a = __builtin_amdgcn_mfma_f32_16x16x32_bf16(qf1, kf1, a, 0, 0, 0);
    sc[t] = a;
  }

  // ---- mask + softmax (C-layout: col j = jbase+t*16+lrow, row i0+quad*4+r) ----
  float sv[6][4];
  float mx[4] = {-1e30f, -1e30f, -1e30f, -1e30f};
#pragma unroll
  for (int t = 0; t < 6; ++t) {
    int j = jbase + t * 16 + lrow;
#pragma unroll
    for (int r = 0; r < 4; ++r) {
      int dji = (i0 + quad * 4 + r) - j;
      bool valid = (j >= 0) && (dji >= 0) && (dji <= 64);
      float s = valid ? sc[t][r] * 0.125f : -1e30f;
      sv[t][r] = s;
      mx[r] = fmaxf(mx[r], s);
    }
  }
#pragma unroll
  for (int r = 0; r < 4; ++r)
#pragma unroll
    for (int off = 8; off > 0; off >>= 1)
      mx[r] = fmaxf(mx[r], __shfl_xor(mx[r], off));

  float ls[4] = {0.f, 0.f, 0.f, 0.f};
#pragma unroll
  for (int t = 0; t < 6; ++t)
#pragma unroll
    for (int r = 0; r < 4; ++r) {
      float e = __expf(sv[t][r] - mx[r]);
      sv[t][r] = e;
      ls[r] += e;
    }
#pragma unroll
  for (int r = 0; r < 4; ++r) {
#pragma unroll
    for (int off = 8; off > 0; off >>= 1)
      ls[r] += __shfl_xor(ls[r], off);
    ls[r] = 1.f / ls[r];
  }
#pragma unroll
  for (int t = 0; t < 6; ++t)
#pragma unroll
    for (int r = 0; r < 4; ++r)
      plds[w][quad * 4 + r][t * 16 + lrow] = f2bf(sv[t][r] * ls[r]);
  __syncthreads();

  // ---- PV: D[m=d][n=q] = sum_j Vs[d][j] * P[q][j] ----
  floatx4 oc[4];
#pragma unroll
  for (int mt = 0; mt < 4; ++mt) oc[mt] = floatx4{0.f, 0.f, 0.f, 0.f};
#pragma unroll
  for (int c = 0; c < 3; ++c) {
    short8 pf = *(const short8*)&plds[w][lrow][c * 32 + quad * 8];
#pragma unroll
    for (int mt = 0; mt < 4; ++mt) {
      short8 vf = *(const short8*)&Vs[(mt * 16 + lrow) * 104 + c * 32 + quad * 8];
      oc[mt] = __builtin_amdgcn_mfma_f32_16x16x32_bf16(vf, pf, oc[mt], 0, 0, 0);
    }
  }

#pragma unroll
  for (int mt = 0; mt < 4; ++mt) {
    ushort4 o;
    o.x = f2bf(oc[mt][0]); o.y = f2bf(oc[mt][1]);
    o.z = f2bf(oc[mt][2]); o.w = f2bf(oc[mt][3]);
    *(ushort4*)(ao + (size_t)(bS + i0 + lrow) * 1024 + h * 64 + mt * 16 + quad * 4) = o;
  }
}

// ---------------------------------------------------------------------------
extern "C" void kernel_launch(void* const* d_in, const int* in_sizes, int n_in,
                              void* d_out, int out_size, void* d_ws, size_t ws_size,
                              hipStream_t stream) {
  const float* x  = (const float*)d_in[0];
  const float* fc = (const float*)d_in[1];
  const float* fs = (const float*)d_in[2];
  const float* wq = (const float*)d_in[3];
  const float* wk = (const float*)d_in[4];
  const float* wv = (const float*)d_in[5];
  const float* wo = (const float*)d_in[6];
  float* out = (float*)d_out;

  // ws: [xb 8M][wqkvT 3M][woT 2M][qb 8M][kb 2M][vT 2M][ao 8M] = 33 MiB
  char* base = (char*)d_ws;
  unsigned short* xb    = (unsigned short*)base;
  unsigned short* wqkvT = (unsigned short*)(base + (8u << 20));
  unsigned short* woT   = (unsigned short*)(base + (11u << 20));
  unsigned short* qb    = (unsigned short*)(base + (13u << 20));
  unsigned short* kb    = (unsigned short*)(base + (21u << 20));
  unsigned short* vT    = (unsigned short*)(base + (23u << 20));
  unsigned short* ao    = (unsigned short*)(base + (25u << 20));

  // 1) prep: cast x + transpose all weights
  prep_kernel<<<4096 + 2560, 256, 0, stream>>>(x, wq, wk, wv, wo, xb, wqkvT, woT);

  // 2) fused QKV GEMM + RoPE + V-transpose (128x128 tiles)
  gemm_qkv_kernel<<<dim3(BS / 128, QS / 128), 256, 0, stream>>>(
      xb, wqkvT, fc, fs, qb, kb, vT);

  // 3) MFMA attention (block-cooperative K/V staging) -> ao bf16
  attn_kernel<<<(BS / 16) * H / 4, 256, 0, stream>>>(qb, kb, vT, ao);

  // 4) output projection -> fp32 (128x128 tiles)
  gemm_bt_kernel<<<dim3(BS / 128, D / 128), 256, 0, stream>>>(ao, woT, out, D);
}

// Round 2
// 133.575 us; speedup vs baseline: 1.0483x; 1.0483x over previous
//
#include <hip/hip_runtime.h>
#include <hip/hip_bf16.h>

constexpr int B = 2, S = 2048, D = 1024;
constexpr int H = 16, KVH = 4, HD = 64;
constexpr int BS = B * S;                 // 4096
constexpr int QS = 1536;                  // fused qkv width

typedef __attribute__((ext_vector_type(8))) short short8;
typedef __attribute__((ext_vector_type(4))) float floatx4;

#define GPTR(p) ((__attribute__((address_space(1))) void*)(p))
#define LPTR(p) ((__attribute__((address_space(3))) void*)(p))

static __device__ __forceinline__ unsigned short f2bf(float f) {
  union { float f; unsigned u; } c{f};
  unsigned r = (c.u + 0x7FFFu + ((c.u >> 16) & 1u)) >> 16;
  return (unsigned short)r;
}

// ---------------------------------------------------------------------------
// Prep: x fp32 -> bf16 (blocks [0,4096)) and all 4 weight transposes
// (blocks [4096, 4096+2560)). fp32 [K=1024,N] -> bf16 [N,1024].
// ---------------------------------------------------------------------------
__global__ __launch_bounds__(256) void prep_kernel(
    const float* __restrict__ x,
    const float* __restrict__ wq, const float* __restrict__ wk,
    const float* __restrict__ wv, const float* __restrict__ wo,
    unsigned short* __restrict__ xb,
    unsigned short* __restrict__ wqkvT, unsigned short* __restrict__ woT) {
  int bz = blockIdx.x;
  if (bz < 4096) {
    int t = bz * 256 + threadIdx.x;
    float4 v = ((const float4*)x)[t];
    ushort4 o;
    o.x = f2bf(v.x); o.y = f2bf(v.y); o.z = f2bf(v.z); o.w = f2bf(v.w);
    ((ushort4*)xb)[t] = o;
    return;
  }
  __shared__ float t[32][33];
  int z = bz - 4096;                 // 0..2559
  int zx = z % 80, zy = z / 80;      // region-select, k-block
  const float* src; unsigned short* dst; int N, dstOff, nb;
  if (zx < 32)      { src = wq; dst = wqkvT; N = 1024; dstOff = 0;    nb = zx; }
  else if (zx < 40) { src = wk; dst = wqkvT; N = 256;  dstOff = 1024; nb = zx - 32; }
  else if (zx < 48) { src = wv; dst = wqkvT; N = 256;  dstOff = 1280; nb = zx - 40; }
  else              { src = wo; dst = woT;   N = 1024; dstOff = 0;    nb = zx - 48; }
  int n0 = nb * 32, k0 = zy * 32;
  int tx = threadIdx.x & 31, ty = threadIdx.x >> 5;
#pragma unroll
  for (int r = 0; r < 4; ++r)
    t[ty + r * 8][tx] = src[(size_t)(k0 + ty + r * 8) * N + n0 + tx];
  __syncthreads();
#pragma unroll
  for (int r = 0; r < 4; ++r)
    dst[(size_t)(dstOff + n0 + ty + r * 8) * D + k0 + tx] = f2bf(t[tx][ty + r * 8]);
}

// ---------------------------------------------------------------------------
// Shared GEMM K-loop (R9-proven): 128x64 tile, BK=128 (four 32-k sections,
// m97 linear [row][32] LDS layout), async global_load_lds staging.
// Grid: blockIdx.x = ROW tile (fast -> XCD partition of A), .y = COL tile.
// ---------------------------------------------------------------------------
#define GEMM_PROLOGUE(Aptr, Btptr)                                            \
  __shared__ unsigned short As[4 * 128 * 32];                                 \
  __shared__ unsigned short Bs[4 * 64 * 32];                                  \
  const int tid = threadIdx.x;                                                \
  const int lane = tid & 63, wvid = tid >> 6;                                 \
  const int wy = wvid >> 1, wx = wvid & 1;                                    \
  const int quad = lane >> 4, lrow = lane & 15;                               \
  const size_t row0 = (size_t)blockIdx.x * 128;                               \
  const size_t col0 = (size_t)blockIdx.y * 64;                                \
  floatx4 acc[4][2];                                                          \
  _Pragma("unroll") for (int i = 0; i < 4; ++i)                               \
    _Pragma("unroll") for (int j = 0; j < 2; ++j)                             \
      acc[i][j] = floatx4{0.f, 0.f, 0.f, 0.f};                                \
  const int arow = wvid * 32 + (lane >> 2);                                   \
  const int brow = wvid * 16 + (lane >> 2);                                   \
  const int schk = (lane & 3) * 8;                                            \
  const unsigned short* gA = (Aptr) + (row0 + arow) * 1024 + schk;            \
  const unsigned short* gB = (Btptr) + (col0 + brow) * 1024 + schk;           \
  char* ldsA = (char*)As + wvid * 2048;                                       \
  char* ldsB = (char*)Bs + wvid * 1024;                                       \
  for (int k0 = 0; k0 < 1024; k0 += 128) {                                    \
    __syncthreads();                                                          \
    _Pragma("unroll") for (int hf = 0; hf < 4; ++hf) {                        \
      __builtin_amdgcn_global_load_lds(GPTR(gA + k0 + hf * 32),               \
                                       LPTR(ldsA + hf * 8192), 16, 0, 0);     \
      __builtin_amdgcn_global_load_lds(GPTR(gA + 16 * 1024 + k0 + hf * 32),   \
                                       LPTR(ldsA + hf * 8192 + 1024), 16, 0, 0); \
      __builtin_amdgcn_global_load_lds(GPTR(gB + k0 + hf * 32),               \
                                       LPTR(ldsB + hf * 4096), 16, 0, 0);     \
    }                                                                         \
    __syncthreads();                                                          \
    _Pragma("unroll") for (int hf = 0; hf < 4; ++hf) {                        \
      short8 af[4], bg[2];                                                    \
      _Pragma("unroll") for (int mi = 0; mi < 4; ++mi)                        \
        af[mi] = *(const short8*)&As[hf * 4096 +                              \
                                     (wy * 64 + mi * 16 + lrow) * 32 + quad * 8]; \
      _Pragma("unroll") for (int ni = 0; ni < 2; ++ni)                        \
        bg[ni] = *(const short8*)&Bs[hf * 2048 +                              \
                                     (wx * 32 + ni * 16 + lrow) * 32 + quad * 8]; \
      _Pragma("unroll") for (int mi = 0; mi < 4; ++mi)                        \
        _Pragma("unroll") for (int ni = 0; ni < 2; ++ni)                      \
          acc[mi][ni] = __builtin_amdgcn_mfma_f32_16x16x32_bf16(              \
              af[mi], bg[ni], acc[mi][ni], 0, 0, 0);                          \
    }                                                                         \
  }

// ---------------------------------------------------------------------------
// Fused QKV GEMM + RoPE + V-transpose.  C[4096,1536] never materialized.
// ---------------------------------------------------------------------------
__global__ __launch_bounds__(256) void gemm_qkv_kernel(
    const unsigned short* __restrict__ A, const unsigned short* __restrict__ Bt,
    const float* __restrict__ cs, const float* __restrict__ sn,
    unsigned short* __restrict__ qb, unsigned short* __restrict__ kb,
    unsigned short* __restrict__ vt) {
  GEMM_PROLOGUE(A, Bt)

  const int col_wave = (int)col0 + wx * 32;     // wave-uniform, within one head
  const int h = col_wave >> 6;
  const int hc = col_wave & 63;
  const int sb = (int)(row0 & 2047) + wy * 64;
  const int bidx = (int)(row0 >> 11);

  if (h < 20) {
    unsigned short* dst = (h < 16) ? qb : kb;
    const int dstride = (h < 16) ? 1024 : 256;
    const int dcol = (h < 16) ? col_wave : (col_wave - 1024);
    const bool ev = (lrow & 1) == 0;
#pragma unroll
    for (int mi = 0; mi < 4; ++mi) {
#pragma unroll
      for (int ni = 0; ni < 2; ++ni) {
        int ff = (hc + ni * 16 + lrow) >> 1;
#pragma unroll
        for (int r = 0; r < 4; ++r) {
          int s = sb + mi * 16 + quad * 4 + r;
          float v = acc[mi][ni][r];
          float p = __shfl_xor(v, 1);
          float c = cs[s * 32 + ff];
          float si = sn[s * 32 + ff];
          float o = ev ? (v * c - p * si) : (v * c + p * si);
          size_t row = row0 + wy * 64 + mi * 16 + quad * 4 + r;
          dst[row * dstride + dcol + ni * 16 + lrow] = f2bf(o);
        }
      }
    }
  } else {
    const int kvh = h - 20;
    const int g = bidx * KVH + kvh;
#pragma unroll
    for (int mi = 0; mi < 4; ++mi) {
#pragma unroll
      for (int ni = 0; ni < 2; ++ni) {
        int d = hc + ni * 16 + lrow;
        int s0 = sb + mi * 16 + quad * 4;
        ushort4 o;
        o.x = f2bf(acc[mi][ni][0]); o.y = f2bf(acc[mi][ni][1]);
        o.z = f2bf(acc[mi][ni][2]); o.w = f2bf(acc[mi][ni][3]);
        *(ushort4*)&vt[((size_t)(g * 64 + d)) * S + s0] = o;
      }
    }
  }
}

// ---------------------------------------------------------------------------
// Output projection GEMM -> fp32 C. Same structure.
// ---------------------------------------------------------------------------
__global__ __launch_bounds__(256) void gemm_bt_kernel(
    const unsigned short* __restrict__ A, const unsigned short* __restrict__ Bt,
    float* __restrict__ C, int N) {
  GEMM_PROLOGUE(A, Bt)

#pragma unroll
  for (int mi = 0; mi < 4; ++mi)
#pragma unroll
    for (int ni = 0; ni < 2; ++ni) {
      size_t col = col0 + wx * 32 + ni * 16 + lrow;
      size_t rowb = row0 + wy * 64 + mi * 16 + quad * 4;
#pragma unroll
      for (int r = 0; r < 4; ++r)
        C[(rowb + r) * N + col] = acc[mi][ni][r];
    }
}

// ---------------------------------------------------------------------------
// MFMA flash attention, block-cooperative K/V LDS staging.
// Block = 4 waves sharing (b, qblk, kvh); wave w handles head 4*kvh + w.
// Valid j-window for queries [i0, i0+15] is exactly [i0-64, i0+15] = 80 rows
// = 5 MFMA tiles (was 6 with a fully-masked leading tile).
// K tile [80][72] (rows j = jbase..jbase+79), V^T tile [64][104] (96-wide
// j staged, right edge clamped to S-8 -> masked, P=0). P cols 80..95 zeroed
// so PV's 3x32-k chunks see P=0 there.
// LDS total 37.3 KB -> 4 blocks/CU at grid 1024.
// ---------------------------------------------------------------------------
__global__ __launch_bounds__(256) void attn_kernel(
    const unsigned short* __restrict__ qb,   // [BS][1024]
    const unsigned short* __restrict__ kb,   // [BS][256]
    const unsigned short* __restrict__ vt,   // [B*KVH][64][S]
    unsigned short* __restrict__ ao) {       // [BS][1024]
  __shared__ __align__(16) unsigned short Ks[80 * 72];     // 11520 B
  __shared__ __align__(16) unsigned short Vs[64 * 104];    // 13312 B
  __shared__ __align__(16) unsigned short plds[4][16][104];// 13312 B
  const int tid = threadIdx.x;
  const int w = tid >> 6, lane = tid & 63;
  const int lrow = lane & 15, quad = lane >> 4;
  const int kvh = blockIdx.x & 3;           // shared across the 4 waves
  const int qblk = blockIdx.x >> 2;
  const int h = kvh * 4 + w;
  const int i0 = (qblk & (S / 16 - 1)) * 16;
  const int b = qblk >> 7;
  const int jbase = i0 - 64;
  const int bS = b * S;

  // ---- cooperative staging: K (80 rows x 8 chunks) and V^T (64 x 12) ----
#pragma unroll
  for (int it = 0; it < 3; ++it) {
    int c = tid + it * 256;                 // 0..767, only 640 used
    if (c < 640) {
      int rr = c >> 3, oo = (c & 7) * 8;    // K: row rr (j = jbase+rr)
      int j = jbase + rr;
      j = j < 0 ? 0 : j;                    // garbage masked later
      *(uint4*)&Ks[rr * 72 + oo] =
          *(const uint4*)&kb[(size_t)(bS + j) * 256 + kvh * 64 + oo];
    }
  }
  const unsigned short* vbase = vt + (size_t)(b * KVH + kvh) * 64 * S;
#pragma unroll
  for (int it = 0; it < 3; ++it) {
    int c = tid + it * 256;                 // 0..767
    int rr = c / 12, oo = c % 12;           // V: d-row rr, j-chunk oo (8-aligned)
    int j = jbase + oo * 8;
    j = j < 0 ? 0 : j;                      // left edge: masked, P=0
    j = j > S - 8 ? S - 8 : j;              // right edge: masked, P=0
    *(uint4*)&Vs[rr * 104 + oo * 8] = *(const uint4*)&vbase[(size_t)rr * S + j];
  }
  __syncthreads();

  // ---- QK^T (K frags from LDS), 5 j-tiles ----
  const unsigned short* qrow = qb + (size_t)(bS + i0 + lrow) * 1024 + h * 64 + quad * 8;
  short8 qf0 = *(const short8*)qrow;
  short8 qf1 = *(const short8*)(qrow + 32);

  floatx4 sc[5];
#pragma unroll
  for (int t = 0; t < 5; ++t) {
    int kr = t * 16 + lrow;
    short8 kf0 = *(const short8*)&Ks[kr * 72 + quad * 8];
    short8 kf1 = *(const short8*)&Ks[kr * 72 + 32 + quad * 8];
    floatx4 a = {0.f, 0.f, 0.f, 0.f};
    a = __builtin_amdgcn_mfma_f32_16x16x32_bf16(qf0, kf0, a, 0, 0, 0);
    a = __builtin_amdgcn_mfma_f32_16x16x32_bf16(qf1, kf1, a, 0, 0, 0);
    sc[t] = a;
  }

  // ---- mask + softmax (C-layout: col j = jbase+t*16+lrow, row i0+quad*4+r) ----
  float sv[5][4];
  float mx[4] = {-1e30f, -1e30f, -1e30f, -1e30f};
#pragma unroll
  for (int t = 0; t < 5; ++t) {
    int j = jbase + t * 16 + lrow;
#pragma unroll
    for (int r = 0; r < 4; ++r) {
      int dji = (i0 + quad * 4 + r) - j;
      bool valid = (j >= 0) && (dji >= 0) && (dji <= 64);
      float s = valid ? sc[t][r] * 0.125f : -1e30f;
      sv[t][r] = s;
      mx[r] = fmaxf(mx[r], s);
    }
  }
#pragma unroll
  for (int r = 0; r < 4; ++r)
#pragma unroll
    for (int off = 8; off > 0; off >>= 1)
      mx[r] = fmaxf(mx[r], __shfl_xor(mx[r], off));

  float ls[4] = {0.f, 0.f, 0.f, 0.f};
#pragma unroll
  for (int t = 0; t < 5; ++t)
#pragma unroll
    for (int r = 0; r < 4; ++r) {
      float e = __expf(sv[t][r] - mx[r]);
      sv[t][r] = e;
      ls[r] += e;
    }
#pragma unroll
  for (int r = 0; r < 4; ++r) {
#pragma unroll
    for (int off = 8; off > 0; off >>= 1)
      ls[r] += __shfl_xor(ls[r], off);
    ls[r] = 1.f / ls[r];
  }
#pragma unroll
  for (int t = 0; t < 5; ++t)
#pragma unroll
    for (int r = 0; r < 4; ++r)
      plds[w][quad * 4 + r][t * 16 + lrow] = f2bf(sv[t][r] * ls[r]);
  // zero P cols 80..95 (PV's third 32-k chunk reads them; V there is garbage)
#pragma unroll
  for (int r = 0; r < 4; ++r)
    plds[w][quad * 4 + r][80 + lrow] = 0;
  __syncthreads();

  // ---- PV: D[m=d][n=q] = sum_j Vs[d][j] * P[q][j] ----
  floatx4 oc[4];
#pragma unroll
  for (int mt = 0; mt < 4; ++mt) oc[mt] = floatx4{0.f, 0.f, 0.f, 0.f};
#pragma unroll
  for (int c = 0; c < 3; ++c) {
    short8 pf = *(const short8*)&plds[w][lrow][c * 32 + quad * 8];
#pragma unroll
    for (int mt = 0; mt < 4; ++mt) {
      short8 vf = *(const short8*)&Vs[(mt * 16 + lrow) * 104 + c * 32 + quad * 8];
      oc[mt] = __builtin_amdgcn_mfma_f32_16x16x32_bf16(vf, pf, oc[mt], 0, 0, 0);
    }
  }

#pragma unroll
  for (int mt = 0; mt < 4; ++mt) {
    ushort4 o;
    o.x = f2bf(oc[mt][0]); o.y = f2bf(oc[mt][1]);
    o.z = f2bf(oc[mt][2]); o.w = f2bf(oc[mt][3]);
    *(ushort4*)(ao + (size_t)(bS + i0 + lrow) * 1024 + h * 64 + mt * 16 + quad * 4) = o;
  }
}

// ---------------------------------------------------------------------------
extern "C" void kernel_launch(void* const* d_in, const int* in_sizes, int n_in,
                              void* d_out, int out_size, void* d_ws, size_t ws_size,
                              hipStream_t stream) {
  const float* x  = (const float*)d_in[0];
  const float* fc = (const float*)d_in[1];
  const float* fs = (const float*)d_in[2];
  const float* wq = (const float*)d_in[3];
  const float* wk = (const float*)d_in[4];
  const float* wv = (const float*)d_in[5];
  const float* wo = (const float*)d_in[6];
  float* out = (float*)d_out;

  // ws: [xb 8M][wqkvT 3M][woT 2M][qb 8M][kb 2M][vT 2M][ao 8M] = 33 MiB
  char* base = (char*)d_ws;
  unsigned short* xb    = (unsigned short*)base;
  unsigned short* wqkvT = (unsigned short*)(base + (8u << 20));
  unsigned short* woT   = (unsigned short*)(base + (11u << 20));
  unsigned short* qb    = (unsigned short*)(base + (13u << 20));
  unsigned short* kb    = (unsigned short*)(base + (21u << 20));
  unsigned short* vT    = (unsigned short*)(base + (23u << 20));
  unsigned short* ao    = (unsigned short*)(base + (25u << 20));

  // 1) prep: cast x + transpose all weights
  prep_kernel<<<4096 + 2560, 256, 0, stream>>>(x, wq, wk, wv, wo, xb, wqkvT, woT);

  // 2) fused QKV GEMM + RoPE + V-transpose (grid = rows x cols, XCD-aware)
  gemm_qkv_kernel<<<dim3(BS / 128, QS / 64), 256, 0, stream>>>(
      xb, wqkvT, fc, fs, qb, kb, vT);

  // 3) MFMA attention (block-cooperative K/V staging) -> ao bf16
  attn_kernel<<<(BS / 16) * H / 4, 256, 0, stream>>>(qb, kb, vT, ao);

  // 4) output projection -> fp32 (grid = rows x cols, XCD-aware)
  gemm_bt_kernel<<<dim3(BS / 128, D / 64), 256, 0, stream>>>(ao, woT, out, D);
}